// Round 1
// baseline (3106.526 us; speedup 1.0000x reference)
//
#include <hip/hip_runtime.h>
#include <hip/hip_bf16.h>

#define HID 128

// ---------------- kernels ----------------

__global__ void k_count_deg(const int* __restrict__ dst, float* __restrict__ deg, int E) {
    int e = blockIdx.x * blockDim.x + threadIdx.x;
    if (e < E) atomicAdd(&deg[dst[e]], 1.0f);
}

__global__ void k_deg_finalize(float* __restrict__ deg, float* __restrict__ dinv,
                               float* __restrict__ invd, int N) {
    int i = blockIdx.x * blockDim.x + threadIdx.x;
    if (i < N) {
        float d = deg[i] + 1.0f;   // +1 self loop
        deg[i] = d;
        dinv[i] = 1.0f / sqrtf(d);
        invd[i] = 1.0f / d;
    }
}

// x = [one_hot(residue,20), pos(3)];  out = x @ W   (W: [23,128] row-major)
__global__ void k_xw_input(const int* __restrict__ residue, const float* __restrict__ pos,
                           const float* __restrict__ W, float* __restrict__ out, int N) {
    int t = blockIdx.x * blockDim.x + threadIdx.x;
    int i = t >> 7, j = t & 127;
    if (i >= N) return;
    int r = residue[i];
    float v = W[r * HID + j];
    v += pos[i * 3 + 0] * W[20 * HID + j];
    v += pos[i * 3 + 1] * W[21 * HID + j];
    v += pos[i * 3 + 2] * W[22 * HID + j];
    out[(size_t)i * HID + j] = v;
}

// agg[dst] += xw[src] * dinv[src]*dinv[dst], edge-parallel, 128 threads/edge
__global__ void k_scatter(const int* __restrict__ src, const int* __restrict__ dst,
                          const float* __restrict__ dinv, const float* __restrict__ xw,
                          float* __restrict__ agg, int E) {
    long long t = (long long)blockIdx.x * blockDim.x + threadIdx.x;
    int e = (int)(t >> 7), j = (int)(t & 127);
    if (e >= E) return;
    int s = src[e], d = dst[e];
    float c = dinv[s] * dinv[d];
    atomicAdd(&agg[(size_t)d * HID + j], xw[(size_t)s * HID + j] * c);
}

// out = relu(agg + xw*invd + b)   (elementwise; out may alias agg or xw)
__global__ void k_finish(const float* __restrict__ agg, const float* __restrict__ xw,
                         const float* __restrict__ invd, const float* __restrict__ b,
                         float* __restrict__ out, int N) {
    int t = blockIdx.x * blockDim.x + threadIdx.x;
    int i = t >> 7, j = t & 127;
    if (i >= N) return;
    float v = agg[(size_t)i * HID + j] + xw[(size_t)i * HID + j] * invd[i] + b[j];
    out[(size_t)i * HID + j] = fmaxf(v, 0.0f);
}

// Y = X @ W  (X:[N,128], W:[128,128] row-major). 256 thr: 2 row-slots x 128 cols,
// each slot does 4 rows (base, base+2, base+4, base+6).
__global__ void k_gemm128(const float* __restrict__ X, const float* __restrict__ W,
                          float* __restrict__ Y, int N) {
    int j = threadIdx.x & 127;
    int slot = threadIdx.x >> 7;
    int base = blockIdx.x * 8 + slot;
    int r0 = base, r1 = base + 2, r2 = base + 4, r3 = base + 6;
    int c0 = min(r0, N - 1), c1 = min(r1, N - 1), c2 = min(r2, N - 1), c3 = min(r3, N - 1);
    float a0 = 0.f, a1 = 0.f, a2 = 0.f, a3 = 0.f;
    for (int k = 0; k < HID; ++k) {
        float w = W[k * HID + j];
        a0 += X[(size_t)c0 * HID + k] * w;
        a1 += X[(size_t)c1 * HID + k] * w;
        a2 += X[(size_t)c2 * HID + k] * w;
        a3 += X[(size_t)c3 * HID + k] * w;
    }
    if (r0 < N) Y[(size_t)r0 * HID + j] = a0;
    if (r1 < N) Y[(size_t)r1 * HID + j] = a1;
    if (r2 < N) Y[(size_t)r2 * HID + j] = a2;
    if (r3 < N) Y[(size_t)r3 * HID + j] = a3;
}

// mean-pool stage 1: run-length compacted atomics (batch is sorted)
#define POOL_CHUNK 64
__global__ void k_pool(const float* __restrict__ x, const int* __restrict__ batch,
                       float* __restrict__ sum, float* __restrict__ cnt, int N) {
    int j = threadIdx.x;                 // 128 threads
    int start = blockIdx.x * POOL_CHUNK;
    int end = start + POOL_CHUNK;
    if (end > N) end = N;
    if (start >= N) return;
    int cg = batch[start];
    float acc = 0.f, c = 0.f;
    for (int i = start; i < end; ++i) {
        int g = batch[i];
        if (g != cg) {
            atomicAdd(&sum[cg * HID + j], acc);
            if (j == 0) atomicAdd(&cnt[cg], c);
            acc = 0.f; c = 0.f; cg = g;
        }
        acc += x[(size_t)i * HID + j];
        c += 1.f;
    }
    atomicAdd(&sum[cg * HID + j], acc);
    if (j == 0) atomicAdd(&cnt[cg], c);
}

__global__ void k_pool_div(const float* __restrict__ sum, const float* __restrict__ cnt,
                           float* __restrict__ pooled, int G) {
    int t = blockIdx.x * blockDim.x + threadIdx.x;
    int g = t >> 7, j = t & 127;
    if (g >= G) return;
    pooled[g * HID + j] = sum[g * HID + j] / fmaxf(cnt[g], 1.0f);
}

// head: h = relu([x_m, ctx] @ W1 + b1);  out = h @ W2 + b2  (W1:[256,128], W2:[128,3])
__global__ void k_head(const float* __restrict__ xm, const int* __restrict__ batch,
                       const float* __restrict__ pooled, const float* __restrict__ W1,
                       const float* __restrict__ b1, const float* __restrict__ W2,
                       const float* __restrict__ b2, float* __restrict__ out, int N) {
    __shared__ float hs[256];
    int slot = threadIdx.x >> 7, j = threadIdx.x & 127;
    int i = blockIdx.x * 2 + slot;
    float h = 0.f;
    if (i < N) {
        int g = batch[i];
        const float* ctx = pooled + g * HID;
        float acc = b1[j];
        const float* xr = xm + (size_t)i * HID;
        for (int k = 0; k < HID; ++k) acc += xr[k] * W1[k * HID + j];
        for (int k = 0; k < HID; ++k) acc += ctx[k] * W1[(HID + k) * HID + j];
        h = fmaxf(acc, 0.f);
    }
    hs[threadIdx.x] = h;
    __syncthreads();
    if (i < N && j < 3) {
        float acc = b2[j];
        const float* hr = hs + slot * HID;
        for (int k = 0; k < HID; ++k) acc += hr[k] * W2[k * 3 + j];
        out[(size_t)i * 3 + j] = acc;
    }
}

// ---------------- launch ----------------

extern "C" void kernel_launch(void* const* d_in, const int* in_sizes, int n_in,
                              void* d_out, int out_size, void* d_ws, size_t ws_size,
                              hipStream_t stream) {
    const int*   residue_p = (const int*)d_in[0];
    const float* pos_p     = (const float*)d_in[1];
    const int*   ei_p      = (const int*)d_in[2];
    const int*   batch_p   = (const int*)d_in[3];
    const int*   residue_m = (const int*)d_in[4];
    const float* pos_m     = (const float*)d_in[5];
    const int*   ei_m      = (const int*)d_in[6];
    const int*   batch_m   = (const int*)d_in[7];
    const float* W_p1 = (const float*)d_in[8];
    const float* b_p1 = (const float*)d_in[9];
    const float* W_p2 = (const float*)d_in[10];
    const float* b_p2 = (const float*)d_in[11];
    const float* W_m1 = (const float*)d_in[12];
    const float* b_m1 = (const float*)d_in[13];
    const float* W_m2 = (const float*)d_in[14];
    const float* b_m2 = (const float*)d_in[15];
    const float* W1   = (const float*)d_in[16];
    const float* b1   = (const float*)d_in[17];
    const float* W2   = (const float*)d_in[18];
    const float* b2   = (const float*)d_in[19];

    const int N_P = in_sizes[0];
    const int E_P = in_sizes[2] / 2;
    const int N_M = in_sizes[4];
    const int E_M = in_sizes[6] / 2;
    const int G = 64;

    char* ws = (char*)d_ws;
    size_t szBuf = (size_t)N_P * HID * sizeof(float);   // 51.2 MB (protein-sized, reused by mm)
    float* bufA = (float*)(ws);
    float* bufB = (float*)(ws + szBuf);
    size_t off = 2 * szBuf;
    auto alloc = [&](size_t bytes) {
        float* p = (float*)(ws + off);
        off += (bytes + 511) & ~size_t(511);
        return p;
    };
    float* deg_p  = alloc((size_t)N_P * 4);
    float* dinv_p = alloc((size_t)N_P * 4);
    float* invd_p = alloc((size_t)N_P * 4);
    float* deg_m  = alloc((size_t)N_M * 4);
    float* dinv_m = alloc((size_t)N_M * 4);
    float* invd_m = alloc((size_t)N_M * 4);
    float* psum   = alloc((size_t)G * HID * 4);
    float* pcnt   = alloc((size_t)G * 4);
    float* pooled = alloc((size_t)G * HID * 4);

    auto run_branch = [&](const int* residue, const float* pos, const int* ei,
                          const float* Wl1, const float* bl1,
                          const float* Wl2, const float* bl2,
                          float* deg, float* dinv, float* invd, int N, int E) {
        const int* srcp = ei;
        const int* dstp = ei + E;
        int nt = N * HID;
        long long et = (long long)E * HID;
        int egrid = (int)((et + 255) / 256);

        hipMemsetAsync(deg, 0, (size_t)N * 4, stream);
        k_count_deg<<<(E + 255) / 256, 256, 0, stream>>>(dstp, deg, E);
        k_deg_finalize<<<(N + 255) / 256, 256, 0, stream>>>(deg, dinv, invd, N);

        // layer 1: xw -> bufA, agg -> bufB, x1 -> bufA (in place)
        k_xw_input<<<(nt + 255) / 256, 256, 0, stream>>>(residue, pos, Wl1, bufA, N);
        hipMemsetAsync(bufB, 0, (size_t)N * HID * 4, stream);
        k_scatter<<<egrid, 256, 0, stream>>>(srcp, dstp, dinv, bufA, bufB, E);
        k_finish<<<(nt + 255) / 256, 256, 0, stream>>>(bufB, bufA, invd, bl1, bufA, N);

        // layer 2: xw2 = x1 @ W2 -> bufB, agg -> bufA, x2 -> bufB (in place)
        k_gemm128<<<(N + 7) / 8, 256, 0, stream>>>(bufA, Wl2, bufB, N);
        hipMemsetAsync(bufA, 0, (size_t)N * HID * 4, stream);
        k_scatter<<<egrid, 256, 0, stream>>>(srcp, dstp, dinv, bufB, bufA, E);
        k_finish<<<(nt + 255) / 256, 256, 0, stream>>>(bufA, bufB, invd, bl2, bufB, N);
        // result: bufB
    };

    // protein branch -> pooled embedding
    run_branch(residue_p, pos_p, ei_p, W_p1, b_p1, W_p2, b_p2,
               deg_p, dinv_p, invd_p, N_P, E_P);
    hipMemsetAsync(psum, 0, (size_t)G * HID * 4, stream);
    hipMemsetAsync(pcnt, 0, (size_t)G * 4, stream);
    k_pool<<<(N_P + POOL_CHUNK - 1) / POOL_CHUNK, 128, 0, stream>>>(bufB, batch_p, psum, pcnt, N_P);
    k_pool_div<<<(G * HID + 255) / 256, 256, 0, stream>>>(psum, pcnt, pooled, G);

    // micromolecule branch
    run_branch(residue_m, pos_m, ei_m, W_m1, b_m1, W_m2, b_m2,
               deg_m, dinv_m, invd_m, N_M, E_M);

    // head
    k_head<<<(N_M + 1) / 2, 256, 0, stream>>>(bufB, batch_m, pooled, W1, b1, W2, b2,
                                              (float*)d_out, N_M);
}

// Round 2
// 1395.917 us; speedup vs baseline: 2.2254x; 2.2254x over previous
//
#include <hip/hip_runtime.h>
#include <hip/hip_bf16.h>

#define HID 128

// ---------------- degree ----------------

__global__ void k_count_deg(const int* __restrict__ dst, int* __restrict__ deg, int E) {
    int e = blockIdx.x * blockDim.x + threadIdx.x;
    if (e < E) atomicAdd(&deg[dst[e]], 1);
}

__global__ void k_deg_finalize(const int* __restrict__ deg, float* __restrict__ dinv,
                               float* __restrict__ invd, int N) {
    int i = blockIdx.x * blockDim.x + threadIdx.x;
    if (i < N) {
        float d = (float)deg[i] + 1.0f;   // +1 self loop
        dinv[i] = 1.0f / sqrtf(d);
        invd[i] = 1.0f / d;
    }
}

// ---------------- exclusive scan (deg -> rowptr) ----------------

#define SCAN_TPB 256
#define SCAN_VPT 4
#define SCAN_BS (SCAN_TPB * SCAN_VPT)

__global__ void k_scan_partial(const int* __restrict__ deg, int* __restrict__ partials, int N) {
    __shared__ int lds[SCAN_TPB];
    int base = blockIdx.x * SCAN_BS + threadIdx.x * SCAN_VPT;
    int s = 0;
    #pragma unroll
    for (int c = 0; c < SCAN_VPT; ++c) { int idx = base + c; if (idx < N) s += deg[idx]; }
    lds[threadIdx.x] = s;
    __syncthreads();
    for (int off = SCAN_TPB / 2; off > 0; off >>= 1) {
        if (threadIdx.x < off) lds[threadIdx.x] += lds[threadIdx.x + off];
        __syncthreads();
    }
    if (threadIdx.x == 0) partials[blockIdx.x] = lds[0];
}

__global__ void k_scan_root(int* __restrict__ partials, int nb) {
    __shared__ int lds[SCAN_TPB];
    int t = threadIdx.x;
    int v = (t < nb) ? partials[t] : 0;
    lds[t] = v;
    __syncthreads();
    for (int off = 1; off < SCAN_TPB; off <<= 1) {
        int add = (t >= off) ? lds[t - off] : 0;
        __syncthreads();
        lds[t] += add;
        __syncthreads();
    }
    if (t < nb) partials[t] = lds[t] - v;   // exclusive
}

__global__ void k_scan_final(const int* __restrict__ deg, const int* __restrict__ partials,
                             int* __restrict__ rowptr, int N) {
    __shared__ int lds[SCAN_TPB];
    int base = blockIdx.x * SCAN_BS + threadIdx.x * SCAN_VPT;
    int c0 = 0, c1 = 0, c2 = 0, c3 = 0;
    if (base + 0 < N) c0 = deg[base + 0];
    if (base + 1 < N) c1 = deg[base + 1];
    if (base + 2 < N) c2 = deg[base + 2];
    if (base + 3 < N) c3 = deg[base + 3];
    int s = c0 + c1 + c2 + c3;
    lds[threadIdx.x] = s;
    __syncthreads();
    for (int off = 1; off < SCAN_TPB; off <<= 1) {
        int add = (threadIdx.x >= off) ? lds[threadIdx.x - off] : 0;
        __syncthreads();
        lds[threadIdx.x] += add;
        __syncthreads();
    }
    int off = lds[threadIdx.x] - s + partials[blockIdx.x];
    if (base + 0 < N) { rowptr[base + 0] = off; off += c0; if (base + 0 == N - 1) rowptr[N] = off; }
    if (base + 1 < N) { rowptr[base + 1] = off; off += c1; if (base + 1 == N - 1) rowptr[N] = off; }
    if (base + 2 < N) { rowptr[base + 2] = off; off += c2; if (base + 2 == N - 1) rowptr[N] = off; }
    if (base + 3 < N) { rowptr[base + 3] = off; off += c3; if (base + 3 == N - 1) rowptr[N] = off; }
}

__global__ void k_fill(const int* __restrict__ src, const int* __restrict__ dst,
                       int* __restrict__ cursor, int* __restrict__ csr_src, int E) {
    int e = blockIdx.x * blockDim.x + threadIdx.x;
    if (e >= E) return;
    int d = dst[e];
    int slot = atomicAdd(&cursor[d], 1);
    csr_src[slot] = src[e];
}

// ---------------- layer-1 aggregation in 24-dim input space ----------------
// z0_i = dinv_i * sum_s dinv_s * x0_s  +  invd_i * x0_i,  x0 = [onehot(20), pos(3)]

__global__ void k_agg23(const int* __restrict__ rowptr, const int* __restrict__ csr_src,
                        const int* __restrict__ residue, const float* __restrict__ pos,
                        const float* __restrict__ dinv, const float* __restrict__ invd,
                        float* __restrict__ z0, int N) {
    __shared__ float accs[256 * 25];   // stride 25: conflict-free
    int t = threadIdx.x;
    int node = blockIdx.x * 256 + t;
    float* acc = accs + t * 25;
    #pragma unroll
    for (int k = 0; k < 24; ++k) acc[k] = 0.f;
    if (node < N) {
        int s0 = rowptr[node], s1 = rowptr[node + 1];
        for (int e = s0; e < s1; ++e) {
            int s = csr_src[e];
            float w = dinv[s];
            acc[residue[s]] += w;
            acc[20] += w * pos[s * 3 + 0];
            acc[21] += w * pos[s * 3 + 1];
            acc[22] += w * pos[s * 3 + 2];
        }
        float di = dinv[node], ii = invd[node];
        #pragma unroll
        for (int k = 0; k < 23; ++k) acc[k] *= di;
        acc[residue[node]] += ii;
        acc[20] += ii * pos[node * 3 + 0];
        acc[21] += ii * pos[node * 3 + 1];
        acc[22] += ii * pos[node * 3 + 2];
    }
    __syncthreads();
    int blockbase = blockIdx.x * 256;
    for (int q = t; q < 256 * 24; q += 256) {
        int row = q / 24, k = q - row * 24;
        int gn = blockbase + row;
        if (gn < N) z0[(size_t)gn * 24 + k] = accs[row * 25 + k];
    }
}

// x1 = relu(z0 @ W[23,128] + b)
#define G24_ROWS 32
__global__ void k_gemm24(const float* __restrict__ z0, const float* __restrict__ W,
                         const float* __restrict__ b, float* __restrict__ x1, int N) {
    __shared__ float Ws[23 * 128];
    __shared__ float zr[G24_ROWS][25];
    int t = threadIdx.x;
    for (int q = t; q < 23 * 128; q += 256) Ws[q] = W[q];
    int blockbase = blockIdx.x * G24_ROWS;
    for (int q = t; q < G24_ROWS * 24; q += 256) {
        int row = q / 24, k = q - row * 24;
        int gn = blockbase + row;
        zr[row][k] = (gn < N) ? z0[(size_t)gn * 24 + k] : 0.f;
    }
    __syncthreads();
    int j = t & 127, slot = t >> 7;
    float bj = b[j];
    for (int r = slot; r < G24_ROWS; r += 2) {
        int gn = blockbase + r;
        if (gn >= N) break;
        float acc = bj;
        #pragma unroll
        for (int k = 0; k < 23; ++k) acc += zr[r][k] * Ws[k * 128 + j];
        x1[(size_t)gn * HID + j] = fmaxf(acc, 0.f);
    }
}

// ---------------- layer-2 aggregation: z_i = dinv_i * sum dinv_s x_s + invd_i * x_i ----------------
// one wave per node, float2 per lane (128 cols)

__global__ void k_agg128(const float* __restrict__ x, const int* __restrict__ rowptr,
                         const int* __restrict__ csr_src, const float* __restrict__ dinv,
                         const float* __restrict__ invd, float* __restrict__ z, int N) {
    int gw = (int)(((long long)blockIdx.x * blockDim.x + threadIdx.x) >> 6);
    int lane = threadIdx.x & 63;
    if (gw >= N) return;
    int s0 = rowptr[gw], s1 = rowptr[gw + 1];
    float ax = 0.f, ay = 0.f;
    int e = s0;
    for (; e + 2 <= s1; e += 2) {
        int sA = csr_src[e], sB = csr_src[e + 1];
        float wA = dinv[sA], wB = dinv[sB];
        float2 vA = ((const float2*)(x + (size_t)sA * HID))[lane];
        float2 vB = ((const float2*)(x + (size_t)sB * HID))[lane];
        ax += vA.x * wA; ay += vA.y * wA;
        ax += vB.x * wB; ay += vB.y * wB;
    }
    if (e < s1) {
        int sA = csr_src[e];
        float wA = dinv[sA];
        float2 vA = ((const float2*)(x + (size_t)sA * HID))[lane];
        ax += vA.x * wA; ay += vA.y * wA;
    }
    float di = dinv[gw], ii = invd[gw];
    float2 vs = ((const float2*)(x + (size_t)gw * HID))[lane];
    float2 o; o.x = ax * di + vs.x * ii; o.y = ay * di + vs.y * ii;
    ((float2*)(z + (size_t)gw * HID))[lane] = o;
}

// x2 = relu(z @ W[128,128] + b)   (2 slots x 4 rows per block)
__global__ void k_gemm128_relu(const float* __restrict__ X, const float* __restrict__ W,
                               const float* __restrict__ b, float* __restrict__ Y, int N) {
    int j = threadIdx.x & 127;
    int slot = threadIdx.x >> 7;
    int base = blockIdx.x * 8 + slot;
    int r0 = base, r1 = base + 2, r2 = base + 4, r3 = base + 6;
    int c0 = min(r0, N - 1), c1 = min(r1, N - 1), c2 = min(r2, N - 1), c3 = min(r3, N - 1);
    float a0 = 0.f, a1 = 0.f, a2 = 0.f, a3 = 0.f;
    for (int k = 0; k < HID; ++k) {
        float w = W[k * HID + j];
        a0 += X[(size_t)c0 * HID + k] * w;
        a1 += X[(size_t)c1 * HID + k] * w;
        a2 += X[(size_t)c2 * HID + k] * w;
        a3 += X[(size_t)c3 * HID + k] * w;
    }
    float bj = b[j];
    if (r0 < N) Y[(size_t)r0 * HID + j] = fmaxf(a0 + bj, 0.f);
    if (r1 < N) Y[(size_t)r1 * HID + j] = fmaxf(a1 + bj, 0.f);
    if (r2 < N) Y[(size_t)r2 * HID + j] = fmaxf(a2 + bj, 0.f);
    if (r3 < N) Y[(size_t)r3 * HID + j] = fmaxf(a3 + bj, 0.f);
}

// ---------------- mean pool ----------------

#define POOL_CHUNK 64
__global__ void k_pool(const float* __restrict__ x, const int* __restrict__ batch,
                       float* __restrict__ sum, float* __restrict__ cnt, int N) {
    int j = threadIdx.x;
    int start = blockIdx.x * POOL_CHUNK;
    int end = start + POOL_CHUNK;
    if (end > N) end = N;
    if (start >= N) return;
    int cg = batch[start];
    float acc = 0.f, c = 0.f;
    for (int i = start; i < end; ++i) {
        int g = batch[i];
        if (g != cg) {
            atomicAdd(&sum[cg * HID + j], acc);
            if (j == 0) atomicAdd(&cnt[cg], c);
            acc = 0.f; c = 0.f; cg = g;
        }
        acc += x[(size_t)i * HID + j];
        c += 1.f;
    }
    atomicAdd(&sum[cg * HID + j], acc);
    if (j == 0) atomicAdd(&cnt[cg], c);
}

__global__ void k_pool_div(const float* __restrict__ sum, const float* __restrict__ cnt,
                           float* __restrict__ pooled, int G) {
    int t = blockIdx.x * blockDim.x + threadIdx.x;
    int g = t >> 7, j = t & 127;
    if (g >= G) return;
    pooled[g * HID + j] = sum[g * HID + j] / fmaxf(cnt[g], 1.0f);
}

// ---------------- head ----------------

__global__ void k_head(const float* __restrict__ xm, const int* __restrict__ batch,
                       const float* __restrict__ pooled, const float* __restrict__ W1,
                       const float* __restrict__ b1, const float* __restrict__ W2,
                       const float* __restrict__ b2, float* __restrict__ out, int N) {
    __shared__ float hs[256];
    int slot = threadIdx.x >> 7, j = threadIdx.x & 127;
    int i = blockIdx.x * 2 + slot;
    float h = 0.f;
    if (i < N) {
        int g = batch[i];
        const float* ctx = pooled + g * HID;
        float acc = b1[j];
        const float* xr = xm + (size_t)i * HID;
        for (int k = 0; k < HID; ++k) acc += xr[k] * W1[k * HID + j];
        for (int k = 0; k < HID; ++k) acc += ctx[k] * W1[(HID + k) * HID + j];
        h = fmaxf(acc, 0.f);
    }
    hs[threadIdx.x] = h;
    __syncthreads();
    if (i < N && j < 3) {
        float acc = b2[j];
        const float* hr = hs + slot * HID;
        for (int k = 0; k < HID; ++k) acc += hr[k] * W2[k * 3 + j];
        out[(size_t)i * 3 + j] = acc;
    }
}

// ---------------- launch ----------------

extern "C" void kernel_launch(void* const* d_in, const int* in_sizes, int n_in,
                              void* d_out, int out_size, void* d_ws, size_t ws_size,
                              hipStream_t stream) {
    const int*   residue_p = (const int*)d_in[0];
    const float* pos_p     = (const float*)d_in[1];
    const int*   ei_p      = (const int*)d_in[2];
    const int*   batch_p   = (const int*)d_in[3];
    const int*   residue_m = (const int*)d_in[4];
    const float* pos_m     = (const float*)d_in[5];
    const int*   ei_m      = (const int*)d_in[6];
    const int*   batch_m   = (const int*)d_in[7];
    const float* W_p1 = (const float*)d_in[8];
    const float* b_p1 = (const float*)d_in[9];
    const float* W_p2 = (const float*)d_in[10];
    const float* b_p2 = (const float*)d_in[11];
    const float* W_m1 = (const float*)d_in[12];
    const float* b_m1 = (const float*)d_in[13];
    const float* W_m2 = (const float*)d_in[14];
    const float* b_m2 = (const float*)d_in[15];
    const float* W1   = (const float*)d_in[16];
    const float* b1   = (const float*)d_in[17];
    const float* W2   = (const float*)d_in[18];
    const float* b2   = (const float*)d_in[19];

    const int N_P = in_sizes[0];
    const int E_P = in_sizes[2] / 2;
    const int N_M = in_sizes[4];
    const int E_M = in_sizes[6] / 2;
    const int G = 64;

    char* ws = (char*)d_ws;
    size_t off = 0;
    auto alloc = [&](size_t bytes) {
        char* p = ws + off;
        off += (bytes + 511) & ~size_t(511);
        return p;
    };
    float* bufA    = (float*)alloc((size_t)N_P * HID * 4);
    float* bufB    = (float*)alloc((size_t)N_P * HID * 4);
    int*   deg     = (int*)  alloc((size_t)N_P * 4);
    float* dinv    = (float*)alloc((size_t)N_P * 4);
    float* invd    = (float*)alloc((size_t)N_P * 4);
    int*   rowptr  = (int*)  alloc((size_t)(N_P + 1) * 4);
    int*   cursor  = (int*)  alloc((size_t)N_P * 4);
    int*   partials= (int*)  alloc(256 * 4);
    int*   csr_src = (int*)  alloc((size_t)E_P * 4);
    float* psum    = (float*)alloc((size_t)G * HID * 4);
    float* pcnt    = (float*)alloc((size_t)G * 4);
    float* pooled  = (float*)alloc((size_t)G * HID * 4);

    auto run_branch = [&](const int* residue, const float* pos, const int* ei,
                          const float* Wl1, const float* bl1,
                          const float* Wl2, const float* bl2, int N, int E) {
        const int* srcp = ei;
        const int* dstp = ei + E;
        int nbp = (N + SCAN_BS - 1) / SCAN_BS;

        // degrees
        hipMemsetAsync(deg, 0, (size_t)N * 4, stream);
        k_count_deg<<<(E + 255) / 256, 256, 0, stream>>>(dstp, deg, E);
        k_deg_finalize<<<(N + 255) / 256, 256, 0, stream>>>(deg, dinv, invd, N);

        // CSR build
        k_scan_partial<<<nbp, SCAN_TPB, 0, stream>>>(deg, partials, N);
        k_scan_root<<<1, SCAN_TPB, 0, stream>>>(partials, nbp);
        k_scan_final<<<nbp, SCAN_TPB, 0, stream>>>(deg, partials, rowptr, N);
        hipMemcpyAsync(cursor, rowptr, (size_t)N * 4, hipMemcpyDeviceToDevice, stream);
        k_fill<<<(E + 255) / 256, 256, 0, stream>>>(srcp, dstp, cursor, csr_src, E);

        // layer 1: agg in 24-dim input space (z0 lives at start of bufB), then gemm -> bufA
        float* z0 = bufB;
        k_agg23<<<(N + 255) / 256, 256, 0, stream>>>(rowptr, csr_src, residue, pos,
                                                     dinv, invd, z0, N);
        k_gemm24<<<(N + G24_ROWS - 1) / G24_ROWS, 256, 0, stream>>>(z0, Wl1, bl1, bufA, N);

        // layer 2: agg x1 -> bufB, gemm+relu -> bufA
        k_agg128<<<(N + 3) / 4, 256, 0, stream>>>(bufA, rowptr, csr_src, dinv, invd, bufB, N);
        k_gemm128_relu<<<(N + 7) / 8, 256, 0, stream>>>(bufB, Wl2, bl2, bufA, N);
        // result: bufA
    };

    // protein branch -> pooled
    run_branch(residue_p, pos_p, ei_p, W_p1, b_p1, W_p2, b_p2, N_P, E_P);
    hipMemsetAsync(psum, 0, (size_t)G * HID * 4, stream);
    hipMemsetAsync(pcnt, 0, (size_t)G * 4, stream);
    k_pool<<<(N_P + POOL_CHUNK - 1) / POOL_CHUNK, 128, 0, stream>>>(bufA, batch_p, psum, pcnt, N_P);
    k_pool_div<<<(G * HID + 255) / 256, 256, 0, stream>>>(psum, pcnt, pooled, G);

    // micromolecule branch
    run_branch(residue_m, pos_m, ei_m, W_m1, b_m1, W_m2, b_m2, N_M, E_M);

    // head
    k_head<<<(N_M + 1) / 2, 256, 0, stream>>>(bufA, batch_m, pooled, W1, b1, W2, b2,
                                              (float*)d_out, N_M);
}

// Round 3
// 835.036 us; speedup vs baseline: 3.7202x; 1.6717x over previous
//
#include <hip/hip_runtime.h>
#include <hip/hip_bf16.h>

#define HID 128

// ---------------- degree ----------------

__global__ void k_count_deg(const int* __restrict__ dst, int* __restrict__ deg, int E) {
    int e = blockIdx.x * blockDim.x + threadIdx.x;
    if (e < E) atomicAdd(&deg[dst[e]], 1);
}

__global__ void k_deg_finalize(const int* __restrict__ deg, float* __restrict__ dinv,
                               float* __restrict__ invd, int N) {
    int i = blockIdx.x * blockDim.x + threadIdx.x;
    if (i < N) {
        float d = (float)deg[i] + 1.0f;   // +1 self loop
        dinv[i] = 1.0f / sqrtf(d);
        invd[i] = 1.0f / d;
    }
}

// ---------------- exclusive scan (deg -> rowptr) ----------------

#define SCAN_TPB 256
#define SCAN_VPT 4
#define SCAN_BS (SCAN_TPB * SCAN_VPT)

__global__ void k_scan_partial(const int* __restrict__ deg, int* __restrict__ partials, int N) {
    __shared__ int lds[SCAN_TPB];
    int base = blockIdx.x * SCAN_BS + threadIdx.x * SCAN_VPT;
    int s = 0;
    #pragma unroll
    for (int c = 0; c < SCAN_VPT; ++c) { int idx = base + c; if (idx < N) s += deg[idx]; }
    lds[threadIdx.x] = s;
    __syncthreads();
    for (int off = SCAN_TPB / 2; off > 0; off >>= 1) {
        if (threadIdx.x < off) lds[threadIdx.x] += lds[threadIdx.x + off];
        __syncthreads();
    }
    if (threadIdx.x == 0) partials[blockIdx.x] = lds[0];
}

__global__ void k_scan_root(int* __restrict__ partials, int nb) {
    __shared__ int lds[SCAN_TPB];
    int t = threadIdx.x;
    int v = (t < nb) ? partials[t] : 0;
    lds[t] = v;
    __syncthreads();
    for (int off = 1; off < SCAN_TPB; off <<= 1) {
        int add = (t >= off) ? lds[t - off] : 0;
        __syncthreads();
        lds[t] += add;
        __syncthreads();
    }
    if (t < nb) partials[t] = lds[t] - v;   // exclusive
}

__global__ void k_scan_final(const int* __restrict__ deg, const int* __restrict__ partials,
                             int* __restrict__ rowptr, int N) {
    __shared__ int lds[SCAN_TPB];
    int base = blockIdx.x * SCAN_BS + threadIdx.x * SCAN_VPT;
    int c0 = 0, c1 = 0, c2 = 0, c3 = 0;
    if (base + 0 < N) c0 = deg[base + 0];
    if (base + 1 < N) c1 = deg[base + 1];
    if (base + 2 < N) c2 = deg[base + 2];
    if (base + 3 < N) c3 = deg[base + 3];
    int s = c0 + c1 + c2 + c3;
    lds[threadIdx.x] = s;
    __syncthreads();
    for (int off = 1; off < SCAN_TPB; off <<= 1) {
        int add = (threadIdx.x >= off) ? lds[threadIdx.x - off] : 0;
        __syncthreads();
        lds[threadIdx.x] += add;
        __syncthreads();
    }
    int off = lds[threadIdx.x] - s + partials[blockIdx.x];
    if (base + 0 < N) { rowptr[base + 0] = off; off += c0; if (base + 0 == N - 1) rowptr[N] = off; }
    if (base + 1 < N) { rowptr[base + 1] = off; off += c1; if (base + 1 == N - 1) rowptr[N] = off; }
    if (base + 2 < N) { rowptr[base + 2] = off; off += c2; if (base + 2 == N - 1) rowptr[N] = off; }
    if (base + 3 < N) { rowptr[base + 3] = off; off += c3; if (base + 3 == N - 1) rowptr[N] = off; }
}

__global__ void k_fill(const int* __restrict__ src, const int* __restrict__ dst,
                       int* __restrict__ cursor, int* __restrict__ csr_src, int E) {
    int e = blockIdx.x * blockDim.x + threadIdx.x;
    if (e >= E) return;
    int d = dst[e];
    int slot = atomicAdd(&cursor[d], 1);
    csr_src[slot] = src[e];
}

// ---------------- layer-1 aggregation in 24-dim input space ----------------

__global__ void k_agg23(const int* __restrict__ rowptr, const int* __restrict__ csr_src,
                        const int* __restrict__ residue, const float* __restrict__ pos,
                        const float* __restrict__ dinv, const float* __restrict__ invd,
                        float* __restrict__ z0, int N) {
    __shared__ float accs[256 * 25];
    int t = threadIdx.x;
    int node = blockIdx.x * 256 + t;
    float* acc = accs + t * 25;
    #pragma unroll
    for (int k = 0; k < 24; ++k) acc[k] = 0.f;
    if (node < N) {
        int s0 = rowptr[node], s1 = rowptr[node + 1];
        for (int e = s0; e < s1; ++e) {
            int s = csr_src[e];
            float w = dinv[s];
            acc[residue[s]] += w;
            acc[20] += w * pos[s * 3 + 0];
            acc[21] += w * pos[s * 3 + 1];
            acc[22] += w * pos[s * 3 + 2];
        }
        float di = dinv[node], ii = invd[node];
        #pragma unroll
        for (int k = 0; k < 23; ++k) acc[k] *= di;
        acc[residue[node]] += ii;
        acc[20] += ii * pos[node * 3 + 0];
        acc[21] += ii * pos[node * 3 + 1];
        acc[22] += ii * pos[node * 3 + 2];
    }
    __syncthreads();
    int blockbase = blockIdx.x * 256;
    for (int q = t; q < 256 * 24; q += 256) {
        int row = q / 24, k = q - row * 24;
        int gn = blockbase + row;
        if (gn < N) z0[(size_t)gn * 24 + k] = accs[row * 25 + k];
    }
}

// x1 = relu(z0 @ W[23,128] + b)
#define G24_ROWS 32
__global__ void k_gemm24(const float* __restrict__ z0, const float* __restrict__ W,
                         const float* __restrict__ b, float* __restrict__ x1, int N) {
    __shared__ float Ws[23 * 128];
    __shared__ float zr[G24_ROWS][25];
    int t = threadIdx.x;
    for (int q = t; q < 23 * 128; q += 256) Ws[q] = W[q];
    int blockbase = blockIdx.x * G24_ROWS;
    for (int q = t; q < G24_ROWS * 24; q += 256) {
        int row = q / 24, k = q - row * 24;
        int gn = blockbase + row;
        zr[row][k] = (gn < N) ? z0[(size_t)gn * 24 + k] : 0.f;
    }
    __syncthreads();
    int j = t & 127, slot = t >> 7;
    float bj = b[j];
    for (int r = slot; r < G24_ROWS; r += 2) {
        int gn = blockbase + r;
        if (gn >= N) break;
        float acc = bj;
        #pragma unroll
        for (int k = 0; k < 23; ++k) acc += zr[r][k] * Ws[k * 128 + j];
        x1[(size_t)gn * HID + j] = fmaxf(acc, 0.f);
    }
}

// ---------------- layer-2 aggregation ----------------

__global__ void k_agg128(const float* __restrict__ x, const int* __restrict__ rowptr,
                         const int* __restrict__ csr_src, const float* __restrict__ dinv,
                         const float* __restrict__ invd, float* __restrict__ z, int N) {
    int gw = (int)(((long long)blockIdx.x * blockDim.x + threadIdx.x) >> 6);
    int lane = threadIdx.x & 63;
    if (gw >= N) return;
    int s0 = rowptr[gw], s1 = rowptr[gw + 1];
    float ax = 0.f, ay = 0.f;
    int e = s0;
    for (; e + 4 <= s1; e += 4) {
        int sA = csr_src[e], sB = csr_src[e + 1], sC = csr_src[e + 2], sD = csr_src[e + 3];
        float wA = dinv[sA], wB = dinv[sB], wC = dinv[sC], wD = dinv[sD];
        float2 vA = ((const float2*)(x + (size_t)sA * HID))[lane];
        float2 vB = ((const float2*)(x + (size_t)sB * HID))[lane];
        float2 vC = ((const float2*)(x + (size_t)sC * HID))[lane];
        float2 vD = ((const float2*)(x + (size_t)sD * HID))[lane];
        ax += vA.x * wA; ay += vA.y * wA;
        ax += vB.x * wB; ay += vB.y * wB;
        ax += vC.x * wC; ay += vC.y * wC;
        ax += vD.x * wD; ay += vD.y * wD;
    }
    for (; e < s1; ++e) {
        int sA = csr_src[e];
        float wA = dinv[sA];
        float2 vA = ((const float2*)(x + (size_t)sA * HID))[lane];
        ax += vA.x * wA; ay += vA.y * wA;
    }
    float di = dinv[gw], ii = invd[gw];
    float2 vs = ((const float2*)(x + (size_t)gw * HID))[lane];
    float2 o; o.x = ax * di + vs.x * ii; o.y = ay * di + vs.y * ii;
    ((float2*)(z + (size_t)gw * HID))[lane] = o;
}

// ---------------- protein layer-2 gemm fused with mean-pool sum ----------------
// x2 = relu(Z@W + b); psum[g] += x2 rows. 32-row tile, 4x4 register blocking.

__global__ void k_gemm_pool(const float* __restrict__ Z, const float* __restrict__ W,
                            const float* __restrict__ b, const int* __restrict__ batch,
                            float* __restrict__ psum, int N) {
    __shared__ float red[8][128];
    int tile = blockIdx.x * 32;
    int cg = threadIdx.x & 31, rg = threadIdx.x >> 5;
    int j0 = cg * 4;
    int r[4]; bool val[4];
    #pragma unroll
    for (int m = 0; m < 4; ++m) {
        int rr = tile + rg * 4 + m;
        val[m] = rr < N;
        r[m] = val[m] ? rr : (N - 1);
    }
    float acc[4][4] = {};
    for (int k4 = 0; k4 < 32; ++k4) {
        int k = k4 * 4;
        float4 w0 = *(const float4*)&W[(k + 0) * HID + j0];
        float4 w1 = *(const float4*)&W[(k + 1) * HID + j0];
        float4 w2 = *(const float4*)&W[(k + 2) * HID + j0];
        float4 w3 = *(const float4*)&W[(k + 3) * HID + j0];
        #pragma unroll
        for (int m = 0; m < 4; ++m) {
            float4 x = *(const float4*)&Z[(size_t)r[m] * HID + k];
            acc[m][0] += x.x * w0.x + x.y * w1.x + x.z * w2.x + x.w * w3.x;
            acc[m][1] += x.x * w0.y + x.y * w1.y + x.z * w2.y + x.w * w3.y;
            acc[m][2] += x.x * w0.z + x.y * w1.z + x.z * w2.z + x.w * w3.z;
            acc[m][3] += x.x * w0.w + x.y * w1.w + x.z * w2.w + x.w * w3.w;
        }
    }
    float4 bb = *(const float4*)&b[j0];
    float bbv[4] = {bb.x, bb.y, bb.z, bb.w};
    float v[4][4];
    #pragma unroll
    for (int m = 0; m < 4; ++m)
        #pragma unroll
        for (int c = 0; c < 4; ++c)
            v[m][c] = fmaxf(acc[m][c] + bbv[c], 0.f);

    int gfirst = batch[tile];
    int glast = batch[min(tile + 31, N - 1)];
    if (gfirst == glast) {
        float s0 = 0.f, s1 = 0.f, s2 = 0.f, s3 = 0.f;
        #pragma unroll
        for (int m = 0; m < 4; ++m) if (val[m]) {
            s0 += v[m][0]; s1 += v[m][1]; s2 += v[m][2]; s3 += v[m][3];
        }
        *(float4*)&red[rg][j0] = make_float4(s0, s1, s2, s3);
        __syncthreads();
        if (threadIdx.x < 128) {
            float tot = 0.f;
            #pragma unroll
            for (int q = 0; q < 8; ++q) tot += red[q][threadIdx.x];
            atomicAdd(&psum[gfirst * HID + threadIdx.x], tot);
        }
    } else {
        #pragma unroll
        for (int m = 0; m < 4; ++m) if (val[m]) {
            int g = batch[r[m]];
            #pragma unroll
            for (int c = 0; c < 4; ++c)
                atomicAdd(&psum[g * HID + j0 + c], v[m][c]);
        }
    }
}

__global__ void k_count_batch(const int* __restrict__ batch, int* __restrict__ pcnt, int N) {
    __shared__ int h[64];
    if (threadIdx.x < 64) h[threadIdx.x] = 0;
    __syncthreads();
    for (int i = blockIdx.x * blockDim.x + threadIdx.x; i < N; i += gridDim.x * blockDim.x)
        atomicAdd(&h[batch[i]], 1);
    __syncthreads();
    if (threadIdx.x < 64 && h[threadIdx.x] > 0)
        atomicAdd(&pcnt[threadIdx.x], h[threadIdx.x]);
}

__global__ void k_pool_div(const float* __restrict__ sum, const int* __restrict__ cnt,
                           float* __restrict__ pooled, int G) {
    int t = blockIdx.x * blockDim.x + threadIdx.x;
    int g = t >> 7, j = t & 127;
    if (g >= G) return;
    pooled[g * HID + j] = sum[g * HID + j] / fmaxf((float)cnt[g], 1.0f);
}

// ctxW[g] = pooled[g] @ W1[128:,:] + b1
__global__ void k_ctxw(const float* __restrict__ pooled, const float* __restrict__ W1,
                       const float* __restrict__ b1, float* __restrict__ ctxW) {
    int g = blockIdx.x, j = threadIdx.x;   // 64 blocks x 128 threads
    float a = b1[j];
    const float* pr = pooled + g * HID;
    #pragma unroll 4
    for (int k = 0; k < HID; ++k) a += pr[k] * W1[(HID + k) * HID + j];
    ctxW[g * HID + j] = a;
}

// ---------------- mm layer-2 gemm fused with head ----------------
// x2 = relu(Z@Wm2 + bm2); h = relu(x2@W1a + ctxW[batch]); out = h@W2 + b2

__global__ void k_mm_tail(const float* __restrict__ Z, const float* __restrict__ Wm2,
                          const float* __restrict__ bm2, const int* __restrict__ batch,
                          const float* __restrict__ ctxW, const float* __restrict__ W1,
                          const float* __restrict__ W2, const float* __restrict__ b2,
                          float* __restrict__ out, int N) {
    __shared__ float Xs[32][132];
    __shared__ float Hs[32][132];
    int tile = blockIdx.x * 32;
    int cg = threadIdx.x & 31, rg = threadIdx.x >> 5;
    int j0 = cg * 4;
    int r[4]; bool val[4];
    #pragma unroll
    for (int m = 0; m < 4; ++m) {
        int rr = tile + rg * 4 + m;
        val[m] = rr < N;
        r[m] = val[m] ? rr : (N - 1);
    }
    // phase 1: x2 tile
    {
        float acc[4][4] = {};
        for (int k4 = 0; k4 < 32; ++k4) {
            int k = k4 * 4;
            float4 w0 = *(const float4*)&Wm2[(k + 0) * HID + j0];
            float4 w1 = *(const float4*)&Wm2[(k + 1) * HID + j0];
            float4 w2 = *(const float4*)&Wm2[(k + 2) * HID + j0];
            float4 w3 = *(const float4*)&Wm2[(k + 3) * HID + j0];
            #pragma unroll
            for (int m = 0; m < 4; ++m) {
                float4 x = *(const float4*)&Z[(size_t)r[m] * HID + k];
                acc[m][0] += x.x * w0.x + x.y * w1.x + x.z * w2.x + x.w * w3.x;
                acc[m][1] += x.x * w0.y + x.y * w1.y + x.z * w2.y + x.w * w3.y;
                acc[m][2] += x.x * w0.z + x.y * w1.z + x.z * w2.z + x.w * w3.z;
                acc[m][3] += x.x * w0.w + x.y * w1.w + x.z * w2.w + x.w * w3.w;
            }
        }
        float4 bb = *(const float4*)&bm2[j0];
        float bbv[4] = {bb.x, bb.y, bb.z, bb.w};
        #pragma unroll
        for (int m = 0; m < 4; ++m) {
            int row = rg * 4 + m;
            *(float4*)&Xs[row][j0] = make_float4(
                fmaxf(acc[m][0] + bbv[0], 0.f), fmaxf(acc[m][1] + bbv[1], 0.f),
                fmaxf(acc[m][2] + bbv[2], 0.f), fmaxf(acc[m][3] + bbv[3], 0.f));
        }
    }
    __syncthreads();
    // phase 2: h tile  (X from LDS, W1a from global)
    {
        float acc[4][4] = {};
        for (int k4 = 0; k4 < 32; ++k4) {
            int k = k4 * 4;
            float4 w0 = *(const float4*)&W1[(k + 0) * HID + j0];
            float4 w1 = *(const float4*)&W1[(k + 1) * HID + j0];
            float4 w2 = *(const float4*)&W1[(k + 2) * HID + j0];
            float4 w3 = *(const float4*)&W1[(k + 3) * HID + j0];
            #pragma unroll
            for (int m = 0; m < 4; ++m) {
                float4 x = *(const float4*)&Xs[rg * 4 + m][k];
                acc[m][0] += x.x * w0.x + x.y * w1.x + x.z * w2.x + x.w * w3.x;
                acc[m][1] += x.x * w0.y + x.y * w1.y + x.z * w2.y + x.w * w3.y;
                acc[m][2] += x.x * w0.z + x.y * w1.z + x.z * w2.z + x.w * w3.z;
                acc[m][3] += x.x * w0.w + x.y * w1.w + x.z * w2.w + x.w * w3.w;
            }
        }
        #pragma unroll
        for (int m = 0; m < 4; ++m) {
            int g = batch[r[m]];
            float4 cx = *(const float4*)&ctxW[g * HID + j0];
            float cxv[4] = {cx.x, cx.y, cx.z, cx.w};
            int row = rg * 4 + m;
            *(float4*)&Hs[row][j0] = make_float4(
                fmaxf(acc[m][0] + cxv[0], 0.f), fmaxf(acc[m][1] + cxv[1], 0.f),
                fmaxf(acc[m][2] + cxv[2], 0.f), fmaxf(acc[m][3] + cxv[3], 0.f));
        }
    }
    __syncthreads();
    // phase 3: out = h @ W2 + b2   (split k over 8 segments per row)
    {
        int row = threadIdx.x >> 3, seg = threadIdx.x & 7;
        float p0 = 0.f, p1 = 0.f, p2 = 0.f;
        #pragma unroll
        for (int kk = 0; kk < 16; ++kk) {
            int k = seg * 16 + kk;
            float hv = Hs[row][k];
            p0 += hv * W2[k * 3 + 0];
            p1 += hv * W2[k * 3 + 1];
            p2 += hv * W2[k * 3 + 2];
        }
        __syncthreads();   // Xs free now
        Xs[row][seg * 3 + 0] = p0;
        Xs[row][seg * 3 + 1] = p1;
        Xs[row][seg * 3 + 2] = p2;
        __syncthreads();
        if (threadIdx.x < 96) {
            int rw = threadIdx.x / 3, c = threadIdx.x - rw * 3;
            int gr = tile + rw;
            if (gr < N) {
                float a = b2[c];
                #pragma unroll
                for (int q = 0; q < 8; ++q) a += Xs[rw][q * 3 + c];
                out[(size_t)gr * 3 + c] = a;
            }
        }
    }
}

// ---------------- launch ----------------

extern "C" void kernel_launch(void* const* d_in, const int* in_sizes, int n_in,
                              void* d_out, int out_size, void* d_ws, size_t ws_size,
                              hipStream_t stream) {
    const int*   residue_p = (const int*)d_in[0];
    const float* pos_p     = (const float*)d_in[1];
    const int*   ei_p      = (const int*)d_in[2];
    const int*   batch_p   = (const int*)d_in[3];
    const int*   residue_m = (const int*)d_in[4];
    const float* pos_m     = (const float*)d_in[5];
    const int*   ei_m      = (const int*)d_in[6];
    const int*   batch_m   = (const int*)d_in[7];
    const float* W_p1 = (const float*)d_in[8];
    const float* b_p1 = (const float*)d_in[9];
    const float* W_p2 = (const float*)d_in[10];
    const float* b_p2 = (const float*)d_in[11];
    const float* W_m1 = (const float*)d_in[12];
    const float* b_m1 = (const float*)d_in[13];
    const float* W_m2 = (const float*)d_in[14];
    const float* b_m2 = (const float*)d_in[15];
    const float* W1   = (const float*)d_in[16];
    const float* b1   = (const float*)d_in[17];
    const float* W2   = (const float*)d_in[18];
    const float* b2   = (const float*)d_in[19];

    const int N_P = in_sizes[0];
    const int E_P = in_sizes[2] / 2;
    const int N_M = in_sizes[4];
    const int E_M = in_sizes[6] / 2;
    const int G = 64;

    char* ws = (char*)d_ws;
    size_t off = 0;
    auto alloc = [&](size_t bytes) {
        char* p = ws + off;
        off += (bytes + 511) & ~size_t(511);
        return p;
    };
    float* bufA    = (float*)alloc((size_t)N_P * HID * 4);
    float* bufB    = (float*)alloc((size_t)N_P * HID * 4);
    int*   deg     = (int*)  alloc((size_t)N_P * 4);
    float* dinv    = (float*)alloc((size_t)N_P * 4);
    float* invd    = (float*)alloc((size_t)N_P * 4);
    int*   rowptr  = (int*)  alloc((size_t)(N_P + 1) * 4);
    int*   cursor  = (int*)  alloc((size_t)N_P * 4);
    int*   partials= (int*)  alloc(256 * 4);
    int*   csr_src = (int*)  alloc((size_t)E_P * 4);
    float* psum    = (float*)alloc((size_t)G * HID * 4);
    int*   pcnt    = (int*)  alloc((size_t)G * 4);
    float* pooled  = (float*)alloc((size_t)G * HID * 4);
    float* ctxW    = (float*)alloc((size_t)G * HID * 4);

    auto build_graph = [&](const int* ei, int N, int E) {
        const int* dstp = ei + E;
        int nbp = (N + SCAN_BS - 1) / SCAN_BS;
        hipMemsetAsync(deg, 0, (size_t)N * 4, stream);
        k_count_deg<<<(E + 255) / 256, 256, 0, stream>>>(dstp, deg, E);
        k_deg_finalize<<<(N + 255) / 256, 256, 0, stream>>>(deg, dinv, invd, N);
        k_scan_partial<<<nbp, SCAN_TPB, 0, stream>>>(deg, partials, N);
        k_scan_root<<<1, SCAN_TPB, 0, stream>>>(partials, nbp);
        k_scan_final<<<nbp, SCAN_TPB, 0, stream>>>(deg, partials, rowptr, N);
        hipMemcpyAsync(cursor, rowptr, (size_t)N * 4, hipMemcpyDeviceToDevice, stream);
        k_fill<<<(E + 255) / 256, 256, 0, stream>>>(ei, dstp, cursor, csr_src, E);
    };

    auto layer_common = [&](const int* residue, const float* pos,
                            const float* Wl1, const float* bl1, int N) {
        // layer 1: agg23 -> bufB(z0), gemm24 -> bufA(x1); layer-2 agg -> bufB(z)
        k_agg23<<<(N + 255) / 256, 256, 0, stream>>>(rowptr, csr_src, residue, pos,
                                                     dinv, invd, bufB, N);
        k_gemm24<<<(N + G24_ROWS - 1) / G24_ROWS, 256, 0, stream>>>(bufB, Wl1, bl1, bufA, N);
        k_agg128<<<(N + 3) / 4, 256, 0, stream>>>(bufA, rowptr, csr_src, dinv, invd, bufB, N);
    };

    // ---- protein branch ----
    build_graph(ei_p, N_P, E_P);
    layer_common(residue_p, pos_p, W_p1, b_p1, N_P);
    hipMemsetAsync(psum, 0, (size_t)G * HID * 4, stream);
    hipMemsetAsync(pcnt, 0, (size_t)G * 4, stream);
    k_gemm_pool<<<(N_P + 31) / 32, 256, 0, stream>>>(bufB, W_p2, b_p2, batch_p, psum, N_P);
    k_count_batch<<<256, 256, 0, stream>>>(batch_p, pcnt, N_P);
    k_pool_div<<<(G * HID + 255) / 256, 256, 0, stream>>>(psum, pcnt, pooled, G);
    k_ctxw<<<G, HID, 0, stream>>>(pooled, W1, b1, ctxW);

    // ---- micromolecule branch ----
    build_graph(ei_m, N_M, E_M);
    layer_common(residue_m, pos_m, W_m1, b_m1, N_M);
    k_mm_tail<<<(N_M + 31) / 32, 256, 0, stream>>>(bufB, W_m2, b_m2, batch_m, ctxW,
                                                   W1, W2, b2, (float*)d_out, N_M);
}